// Round 20
// baseline (178.843 us; speedup 1.0000x reference)
//
#include <hip/hip_runtime.h>
#include <math.h>

#define N_TOK 16384
#define HDIM  2048
#define NEXP  64
#define TOPK  8
#define NKS   4             // K split factor
#define KSEG  (HDIM / NKS)  // 512 k per block
#define KCH   32            // k per LDS chunk
#define NCH   (KSEG / KCH)  // 16

// d_ws layout:
//   [0, 32 MiB)   : part  — partial logits f64 [NKS][N_TOK][64]
//   [33 MiB, ...) : stats — f32 probsum[64], counts[64]; +4 KiB: bench sink
#define PART_OFF  0
#define STATS_OFF (33u << 20)

typedef double d4 __attribute__((ext_vector_type(4)));

// In-wave MFMA layout derivation (exact integer arithmetic, asymmetric A/B).
// Same hypothesis space/order as the R8-R18 probe -> same flag on this HW.
__device__ __forceinline__ int derive_flag() {
    const int l = threadIdx.x & 63;
    const int i16 = l & 15, q = l >> 4;
    const int r4 = l >> 2,  m4 = l & 3;
    int fv = 0;
#pragma unroll
    for (int ai = 0; ai < 2; ++ai)
#pragma unroll
    for (int bi = 0; bi < 2; ++bi) {
        const int ra = ai ? r4 : i16, ka = ai ? m4 : q;
        const int cb = bi ? r4 : i16, kb = bi ? m4 : q;
        double a = (double)(ra * 4 + ka + 1);            // A[ra][ka]
        double b = (double)((kb + 1) * 100 + 3 * cb);    // B[kb][cb]
        d4 acc = {0., 0., 0., 0.};
        acc = __builtin_amdgcn_mfma_f64_16x16x4f64(a, b, acc, 0, 0, 0);
#pragma unroll
        for (int sf = 0; sf < 2; ++sf)
#pragma unroll
        for (int tr = 0; tr < 2; ++tr) {
            int ok = 1;
#pragma unroll
            for (int r = 0; r < 4; ++r) {
                const int p   = sf ? (q + 4 * r) : (4 * q + r);
                const int row = tr ? i16 : p;
                const int col = tr ? p : i16;
                double ref = 0.0;
#pragma unroll
                for (int k = 0; k < 4; ++k)
                    ref += (double)(row * 4 + k + 1) * (double)((k + 1) * 100 + 3 * col);
                ok &= (acc[r] == ref);
            }
            if (__all(ok) && fv == 0) fv = 1 + ai * 8 + bi * 4 + sf * 2 + tr;
        }
    }
    return fv;
}

__device__ __forceinline__ void stage_store(double (*Xb)[34], double (*Wb)[34],
                                            int sr, int sc, float4 px, float4 pw) {
    double2 d0, d1;
    d0.x = (double)px.x; d0.y = (double)px.y;
    d1.x = (double)px.z; d1.y = (double)px.w;
    *(double2*)&Xb[sr][sc]     = d0;
    *(double2*)&Xb[sr][sc + 2] = d1;
    d0.x = (double)pw.x; d0.y = (double)pw.y;
    d1.x = (double)pw.z; d1.y = (double)pw.w;
    *(double2*)&Wb[sr][sc]     = d0;
    *(double2*)&Wb[sr][sc + 2] = d1;
}

__device__ __forceinline__ void mfma_chunk(const double (*Xb)[34], const double (*Wb)[34],
                                           int wr, int wc, int ra, int cb, int ka, int kb,
                                           d4& acc0, d4& acc1) {
    const double* qa0 = &Xb[wr * 32 + ra][ka];
    const double* qa1 = &Xb[wr * 32 + 16 + ra][ka];
    const double* qb0 = &Wb[wc * 16 + cb][kb];
#pragma unroll
    for (int kq = 0; kq < 8; ++kq) {                 // 8 K=4 steps: 3 b64 reads, 2 MFMAs
        double a0 = qa0[4 * kq];
        double a1 = qa1[4 * kq];
        double b0 = qb0[4 * kq];
        acc0 = __builtin_amdgcn_mfma_f64_16x16x4f64(a0, b0, acc0, 0, 0, 0);
        acc1 = __builtin_amdgcn_mfma_f64_16x16x4f64(a1, b0, acc1, 0, 0, 0);
    }
}

// MFMA f64 GEMM — R18-exact (best measured: 87.5 us, MfmaUtil 64.5%). FROZEN.
// R12 geometry + double-buffered LDS (one barrier/chunk). Block 512 thr =
// 8 waves in 2(tok)x4(exp); tile 64x64x512k; grid 1024.
__global__ __launch_bounds__(512, 4) void gemm_mfma_kernel(const float* __restrict__ X,
                                                           const float* __restrict__ W,
                                                           double* __restrict__ part) {
    const int f = derive_flag();
    if (f == 0) return;                              // layout unresolved -> VALU path
    const int fb = f - 1;
    const int ai = (fb >> 3) & 1, bi = (fb >> 2) & 1;
    const int sf = (fb >> 1) & 1, tr = fb & 1;

    const int tt  = blockIdx.x >> 2;
    const int ks  = blockIdx.x & 3;
    const int tid = threadIdx.x;
    const int l   = tid & 63;
    const int wv  = tid >> 6;                        // 0..7
    const int wr  = wv >> 2;                         // 0..1: 32-token group
    const int wc  = wv & 3;                          // 0..3: 16-expert group
    const int tok0 = tt * 64;
    const int k0   = ks * KSEG;

    const int i16 = l & 15, q = l >> 4, r4 = l >> 2, m4 = l & 3;
    const int ra = ai ? r4 : i16, ka = ai ? m4 : q;  // A element this lane feeds
    const int cb = bi ? r4 : i16, kb = bi ? m4 : q;  // B element this lane feeds

    __shared__ double Xs[2][64][34];                 // double-buffered
    __shared__ double Ws[2][64][34];

    d4 acc0 = {0., 0., 0., 0.};
    d4 acc1 = {0., 0., 0., 0.};

    // staging: thread -> row tid>>3 (0..63), cols 4*(tid&7)..+3 (one float4 each)
    const int sr = tid >> 3;
    const int sc = (tid & 7) * 4;
    const float* xg = X + (size_t)(tok0 + sr) * HDIM + k0 + sc;
    const float* wg = W + (size_t)sr * HDIM + k0 + sc;

    // prologue: chunk0 -> buf0; chunk1 -> regs B
    float4 pxA = *(const float4*)xg;
    float4 pwA = *(const float4*)wg;
    float4 pxB = *(const float4*)(xg + KCH);
    float4 pwB = *(const float4*)(wg + KCH);
    stage_store(Xs[0], Ws[0], sr, sc, pxA, pwA);
    __syncthreads();

    for (int c = 0; c < NCH; c += 2) {
        // even: compute buf0 (chunk c); B holds c+1; load c+2 -> A
        if (c + 2 < NCH) {
            pxA = *(const float4*)(xg + (c + 2) * KCH);
            pwA = *(const float4*)(wg + (c + 2) * KCH);
        }
        mfma_chunk(Xs[0], Ws[0], wr, wc, ra, cb, ka, kb, acc0, acc1);
        stage_store(Xs[1], Ws[1], sr, sc, pxB, pwB);     // chunk c+1 (c+1<NCH always)
        __syncthreads();
        // odd: compute buf1 (chunk c+1); A holds c+2; load c+3 -> B
        if (c + 3 < NCH) {
            pxB = *(const float4*)(xg + (c + 3) * KCH);
            pwB = *(const float4*)(wg + (c + 3) * KCH);
        }
        mfma_chunk(Xs[1], Ws[1], wr, wc, ra, cb, ka, kb, acc0, acc1);
        if (c + 2 < NCH) {
            stage_store(Xs[0], Ws[0], sr, sc, pxA, pwA); // chunk c+2
            __syncthreads();
        }
    }

    double* pbase = part + (size_t)ks * N_TOK * NEXP;
#pragma unroll
    for (int rt = 0; rt < 2; ++rt) {
        const d4 accv = rt == 0 ? acc0 : acc1;
#pragma unroll
        for (int r = 0; r < 4; ++r) {
            const int p    = sf ? (q + 4 * r) : (4 * q + r);
            const int dtok = tr ? i16 : p;
            const int dex  = tr ? p : i16;
            const int tok  = tok0 + wr * 32 + rt * 16 + dtok;
            const int ex   = wc * 16 + dex;
            pbase[(size_t)tok * NEXP + ex] = accv[r];
        }
    }
}

// VALU fallback (R7 structure, proven math). Doubles as stats zeroer.
// Runs the full GEMM only if the MFMA layout is unresolved on this HW.
__global__ __launch_bounds__(512, 4) void gemm_valu_kernel(const float* __restrict__ X,
                                                           const float* __restrict__ W,
                                                           double* __restrict__ part,
                                                           float* __restrict__ stats) {
    if (blockIdx.x == 0 && threadIdx.x < 128)
        stats[threadIdx.x] = 0.f;                    // probsum + counts
    if (derive_flag() != 0) return;                  // MFMA path verified -> skip
    const int tt   = blockIdx.x >> 2;
    const int ks   = blockIdx.x & 3;
    const int tid  = threadIdx.x;
    const int lane = tid & 63;                       // expert
    const int wv   = tid >> 6;                       // 0..7
    const int tok0 = tt * 64;
    const int k0   = ks * KSEG;

    __shared__ double xs[64][18];
    __shared__ double wsh[16][66];

    double acc[8];
#pragma unroll
    for (int t = 0; t < 8; ++t) acc[t] = 0.0;

    const int sx_tok = tid >> 3;
    const int sx_k   = (tid & 7) * 2;
    const float* xg  = X + (size_t)(tok0 + sx_tok) * HDIM + k0 + sx_k;
    const int sw_k = tid >> 5;                       // 0..15
    const int sw_e = (tid & 31) * 2;                 // 0..62
    const float* wg0 = W + (size_t)sw_e * HDIM + k0 + sw_k;
    const float* wg1 = W + (size_t)(sw_e + 1) * HDIM + k0 + sw_k;

    float2 px = *(const float2*)xg;
    float  pa = *wg0, pb2 = *wg1;

    for (int c = 0; c < KSEG / 16; ++c) {
        __syncthreads();
        {
            double2 xv; xv.x = (double)px.x; xv.y = (double)px.y;
            *(double2*)&xs[sx_tok][sx_k] = xv;
            double2 wv2; wv2.x = (double)pa; wv2.y = (double)pb2;
            *(double2*)&wsh[sw_k][sw_e] = wv2;
        }
        __syncthreads();
        if (c + 1 < KSEG / 16) {
            px  = *(const float2*)(xg + (c + 1) * 16);
            pa  = wg0[(c + 1) * 16];
            pb2 = wg1[(c + 1) * 16];
        }
        double wr_[16];
#pragma unroll
        for (int j = 0; j < 16; ++j) wr_[j] = wsh[j][lane];
#pragma unroll
        for (int t = 0; t < 8; ++t) {
            const int trr = wv * 8 + t;
#pragma unroll
            for (int kp = 0; kp < 8; ++kp) {
                double2 xv = *(const double2*)&xs[trr][kp * 2];
                acc[t] = fma(xv.x, wr_[kp * 2],     acc[t]);
                acc[t] = fma(xv.y, wr_[kp * 2 + 1], acc[t]);
            }
        }
    }

    double* pb = part + ((size_t)ks * N_TOK + tok0 + wv * 8) * NEXP + lane;
#pragma unroll
    for (int t = 0; t < 8; ++t)
        pb[(size_t)t * NEXP] = acc[t];
}

// Top-k (R17-proven, ~15-18 us): 16 tok/block, 2-token-interleaved proven
// ladders (f32 score comparator, ties -> min idx), no fence/counter.
__global__ __launch_bounds__(256) void topk_kernel(const double* __restrict__ part,
                                                   float* __restrict__ outIdx,
                                                   float* __restrict__ outW,
                                                   float* __restrict__ stats) {
    __shared__ float sc_s[16][65];
    __shared__ float lds_counts[NEXP];
    __shared__ float psum_part[4][NEXP];
    const int tid  = threadIdx.x;
    const int lane = tid & 63;
    const int w    = tid >> 6;
    if (tid < NEXP) lds_counts[tid] = 0.f;

    const int t0 = blockIdx.x * 16;
#pragma unroll
    for (int p = 0; p < 4; ++p) {
        const int idx = p * 256 + tid;               // 0..1023
        const int t   = idx >> 6;
        const int e   = idx & 63;
        const double* pp = part + ((size_t)(t0 + t)) * NEXP + e;
        double l = (pp[0] + pp[(size_t)N_TOK * NEXP]) +
                   (pp[2 * (size_t)N_TOK * NEXP] + pp[3 * (size_t)N_TOK * NEXP]);
        sc_s[t][e] = (float)(1.0 / (1.0 + exp(-l)));
    }
    __syncthreads();

    float ps = 0.f;
#pragma unroll
    for (int i = 0; i < 4; i += 2) {                 // two tokens interleaved
        const int tA = w * 4 + i, tB = tA + 1;
        float sA = sc_s[tA][lane], sB = sc_s[tB][lane];

        float rsA = sA, rsB = sB;
#pragma unroll
        for (int off = 32; off; off >>= 1) {
            rsA += __shfl_xor(rsA, off);
            rsB += __shfl_xor(rsB, off);
        }
        ps += sA / (rsA + 1e-9f) + sB / (rsB + 1e-9f);

        float curA = sA, curB = sB;
        float denA = 0.f, denB = 0.f;
        int   wiA = 0, wiB = 0;
        float wvA = 0.f, wvB = 0.f;
#pragma unroll
        for (int k = 0; k < TOPK; ++k) {
            float mA = curA; int miA = lane;
            float mB = curB; int miB = lane;
#pragma unroll
            for (int off = 32; off; off >>= 1) {     // argmax, ties -> min idx
                float omA = __shfl_xor(mA, off);
                int   oiA = __shfl_xor(miA, off);
                float omB = __shfl_xor(mB, off);
                int   oiB = __shfl_xor(miB, off);
                if (omA > mA || (omA == mA && oiA < miA)) { mA = omA; miA = oiA; }
                if (omB > mB || (omB == mB && oiB < miB)) { mB = omB; miB = oiB; }
            }
            denA += mA; denB += mB;
            if (lane == k)   { wiA = miA; wvA = mA; wiB = miB; wvB = mB; }
            if (lane == miA) curA = -1e30f;
            if (lane == miB) curB = -1e30f;
        }
        if (lane < TOPK) {
            const int ta = t0 + tA, tb = t0 + tB;
            outIdx[(size_t)ta * TOPK + lane] = (float)wiA;
            outW  [(size_t)ta * TOPK + lane] = wvA / (denA + 1e-9f);
            outIdx[(size_t)tb * TOPK + lane] = (float)wiB;
            outW  [(size_t)tb * TOPK + lane] = wvB / (denB + 1e-9f);
            atomicAdd(&lds_counts[wiA], 1.f);
            atomicAdd(&lds_counts[wiB], 1.f);
        }
    }
    psum_part[w][lane] = ps;
    __syncthreads();
    if (tid < NEXP) {
        float tot = psum_part[0][tid] + psum_part[1][tid] +
                    psum_part[2][tid] + psum_part[3][tid];
        atomicAdd(&stats[tid], tot);                  // probsum
        atomicAdd(&stats[NEXP + tid], lds_counts[tid]); // counts
    }
}

// Separate aux kernel: dispatch boundary provides cross-XCD visibility of
// topk's device-scope atomics — no per-block fence (R15/R16 lesson).
__global__ void aux_kernel(const float* __restrict__ stats, float* __restrict__ out) {
    const int e = threadIdx.x;                        // 64 threads
    float prob = stats[e] / (float)N_TOK;
    float cnt  = stats[NEXP + e];
    float loadf = cnt / ((float)N_TOK * TOPK);
    float S = prob;
#pragma unroll
    for (int off = 32; off; off >>= 1) S += __shfl_xor(S, off);
    float pn = prob / (S + 1e-9f);
    float v  = loadf * pn;
#pragma unroll
    for (int off = 32; off; off >>= 1) v += __shfl_xor(v, off);
    if (e == 0) out[2 * N_TOK * TOPK] = 0.001f * v * (float)NEXP;
}

// f64 MFMA issue-rate microbenchmark: register operands only, no LDS, no
// barriers; 4 independent chains/wave (the real gemm's dependency shape).
// 256 MFMAs/wave x 4096 waves = 1.048M MFMAs = 2.147 TFLOP.
// Nominal 78.6 TF (64 cyc repeat) -> 27.3 us; 2/3 rate -> 40.9 us.
// Observed via delta in total duration vs R18 baseline (132.1 us).
__global__ __launch_bounds__(256) void mfma_bench_kernel(double* __restrict__ sink) {
    const int l = threadIdx.x & 63;
    double a = (double)(l + 1) * 0.5;
    double b = (double)((l ^ 21) + 3) * 0.25;
    d4 c0 = {0., 0., 0., 0.}, c1 = {0., 0., 0., 0.};
    d4 c2 = {0., 0., 0., 0.}, c3 = {0., 0., 0., 0.};
#pragma unroll 1
    for (int t = 0; t < 64; ++t) {
        c0 = __builtin_amdgcn_mfma_f64_16x16x4f64(a, b, c0, 0, 0, 0);
        c1 = __builtin_amdgcn_mfma_f64_16x16x4f64(a, b, c1, 0, 0, 0);
        c2 = __builtin_amdgcn_mfma_f64_16x16x4f64(a, b, c2, 0, 0, 0);
        c3 = __builtin_amdgcn_mfma_f64_16x16x4f64(a, b, c3, 0, 0, 0);
    }
    double s = c0[0] + c1[1] + c2[2] + c3[3];
    if (threadIdx.x == 0) sink[blockIdx.x] = s;
}

extern "C" void kernel_launch(void* const* d_in, const int* in_sizes, int n_in,
                              void* d_out, int out_size, void* d_ws, size_t ws_size,
                              hipStream_t stream) {
    (void)in_sizes; (void)n_in; (void)out_size; (void)ws_size;
    const float* X = (const float*)d_in[0];
    const float* W = (const float*)d_in[1];
    float* out = (float*)d_out;
    char*  ws  = (char*)d_ws;
    double* part  = (double*)(ws + PART_OFF);
    float*  stats = (float*)(ws + STATS_OFF);
    double* sink  = (double*)(ws + STATS_OFF + 4096);

    gemm_mfma_kernel<<<1024, 512, 0, stream>>>(X, W, part);
    gemm_valu_kernel<<<1024, 512, 0, stream>>>(X, W, part, stats);
    topk_kernel<<<1024, 256, 0, stream>>>(part, out, out + N_TOK * TOPK, stats);
    aux_kernel<<<1, 64, 0, stream>>>(stats, out);
    mfma_bench_kernel<<<1024, 256, 0, stream>>>(sink);   // probe: read via total-dur delta
}

// Round 21
// 131.414 us; speedup vs baseline: 1.3609x; 1.3609x over previous
//
#include <hip/hip_runtime.h>
#include <math.h>

#define N_TOK 16384
#define HDIM  2048
#define NEXP  64
#define TOPK  8
#define NKS   4             // K split factor
#define KSEG  (HDIM / NKS)  // 512 k per block
#define KCH   32            // k per LDS chunk
#define NCH   (KSEG / KCH)  // 16

// d_ws layout:
//   [0, 32 MiB)   : part  — partial logits f64 [NKS][N_TOK][64]
//   [33 MiB, ...) : stats — f32 probsum[64], counts[64]
#define PART_OFF  0
#define STATS_OFF (33u << 20)

typedef double d4 __attribute__((ext_vector_type(4)));

// In-wave MFMA layout derivation (exact integer arithmetic, asymmetric A/B).
// Same hypothesis space/order as the R8-R19 probe -> same flag on this HW.
__device__ __forceinline__ int derive_flag() {
    const int l = threadIdx.x & 63;
    const int i16 = l & 15, q = l >> 4;
    const int r4 = l >> 2,  m4 = l & 3;
    int fv = 0;
#pragma unroll
    for (int ai = 0; ai < 2; ++ai)
#pragma unroll
    for (int bi = 0; bi < 2; ++bi) {
        const int ra = ai ? r4 : i16, ka = ai ? m4 : q;
        const int cb = bi ? r4 : i16, kb = bi ? m4 : q;
        double a = (double)(ra * 4 + ka + 1);            // A[ra][ka]
        double b = (double)((kb + 1) * 100 + 3 * cb);    // B[kb][cb]
        d4 acc = {0., 0., 0., 0.};
        acc = __builtin_amdgcn_mfma_f64_16x16x4f64(a, b, acc, 0, 0, 0);
#pragma unroll
        for (int sf = 0; sf < 2; ++sf)
#pragma unroll
        for (int tr = 0; tr < 2; ++tr) {
            int ok = 1;
#pragma unroll
            for (int r = 0; r < 4; ++r) {
                const int p   = sf ? (q + 4 * r) : (4 * q + r);
                const int row = tr ? i16 : p;
                const int col = tr ? p : i16;
                double ref = 0.0;
#pragma unroll
                for (int k = 0; k < 4; ++k)
                    ref += (double)(row * 4 + k + 1) * (double)((k + 1) * 100 + 3 * col);
                ok &= (acc[r] == ref);
            }
            if (__all(ok) && fv == 0) fv = 1 + ai * 8 + bi * 4 + sf * 2 + tr;
        }
    }
    return fv;
}

__device__ __forceinline__ void stage_store(double (*Xb)[34], double (*Wb)[34],
                                            int sr, int sc, float4 px, float4 pw) {
    double2 d0, d1;
    d0.x = (double)px.x; d0.y = (double)px.y;
    d1.x = (double)px.z; d1.y = (double)px.w;
    *(double2*)&Xb[sr][sc]     = d0;
    *(double2*)&Xb[sr][sc + 2] = d1;
    d0.x = (double)pw.x; d0.y = (double)pw.y;
    d1.x = (double)pw.z; d1.y = (double)pw.w;
    *(double2*)&Wb[sr][sc]     = d0;
    *(double2*)&Wb[sr][sc + 2] = d1;
}

__device__ __forceinline__ void mfma_chunk(const double (*Xb)[34], const double (*Wb)[34],
                                           int wr, int wc, int ra, int cb, int ka, int kb,
                                           d4& acc0, d4& acc1) {
    const double* qa0 = &Xb[wr * 32 + ra][ka];
    const double* qa1 = &Xb[wr * 32 + 16 + ra][ka];
    const double* qb0 = &Wb[wc * 16 + cb][kb];
#pragma unroll
    for (int kq = 0; kq < 8; ++kq) {                 // 8 K=4 steps: 3 b64 reads, 2 MFMAs
        double a0 = qa0[4 * kq];
        double a1 = qa1[4 * kq];
        double b0 = qb0[4 * kq];
        acc0 = __builtin_amdgcn_mfma_f64_16x16x4f64(a0, b0, acc0, 0, 0, 0);
        acc1 = __builtin_amdgcn_mfma_f64_16x16x4f64(a1, b0, acc1, 0, 0, 0);
    }
}

// MFMA f64 GEMM — R18-exact, FINAL. 87.5 us = ~100% of the MEASURED f64
// MFMA issue-rate ceiling (R20 register-only ubench: ~46 TF effective,
// ~0.6x nominal — the instruction, not the schedule, is the limit).
// R12 geometry + double-buffered LDS (one barrier/chunk). Block 512 thr =
// 8 waves in 2(tok)x4(exp); tile 64x64x512k; grid 1024.
__global__ __launch_bounds__(512, 4) void gemm_mfma_kernel(const float* __restrict__ X,
                                                           const float* __restrict__ W,
                                                           double* __restrict__ part) {
    const int f = derive_flag();
    if (f == 0) return;                              // layout unresolved -> VALU path
    const int fb = f - 1;
    const int ai = (fb >> 3) & 1, bi = (fb >> 2) & 1;
    const int sf = (fb >> 1) & 1, tr = fb & 1;

    const int tt  = blockIdx.x >> 2;
    const int ks  = blockIdx.x & 3;
    const int tid = threadIdx.x;
    const int l   = tid & 63;
    const int wv  = tid >> 6;                        // 0..7
    const int wr  = wv >> 2;                         // 0..1: 32-token group
    const int wc  = wv & 3;                          // 0..3: 16-expert group
    const int tok0 = tt * 64;
    const int k0   = ks * KSEG;

    const int i16 = l & 15, q = l >> 4, r4 = l >> 2, m4 = l & 3;
    const int ra = ai ? r4 : i16, ka = ai ? m4 : q;  // A element this lane feeds
    const int cb = bi ? r4 : i16, kb = bi ? m4 : q;  // B element this lane feeds

    __shared__ double Xs[2][64][34];                 // double-buffered
    __shared__ double Ws[2][64][34];

    d4 acc0 = {0., 0., 0., 0.};
    d4 acc1 = {0., 0., 0., 0.};

    // staging: thread -> row tid>>3 (0..63), cols 4*(tid&7)..+3 (one float4 each)
    const int sr = tid >> 3;
    const int sc = (tid & 7) * 4;
    const float* xg = X + (size_t)(tok0 + sr) * HDIM + k0 + sc;
    const float* wg = W + (size_t)sr * HDIM + k0 + sc;

    // prologue: chunk0 -> buf0; chunk1 -> regs B
    float4 pxA = *(const float4*)xg;
    float4 pwA = *(const float4*)wg;
    float4 pxB = *(const float4*)(xg + KCH);
    float4 pwB = *(const float4*)(wg + KCH);
    stage_store(Xs[0], Ws[0], sr, sc, pxA, pwA);
    __syncthreads();

    for (int c = 0; c < NCH; c += 2) {
        // even: compute buf0 (chunk c); B holds c+1; load c+2 -> A
        if (c + 2 < NCH) {
            pxA = *(const float4*)(xg + (c + 2) * KCH);
            pwA = *(const float4*)(wg + (c + 2) * KCH);
        }
        mfma_chunk(Xs[0], Ws[0], wr, wc, ra, cb, ka, kb, acc0, acc1);
        stage_store(Xs[1], Ws[1], sr, sc, pxB, pwB);     // chunk c+1 (c+1<NCH always)
        __syncthreads();
        // odd: compute buf1 (chunk c+1); A holds c+2; load c+3 -> B
        if (c + 3 < NCH) {
            pxB = *(const float4*)(xg + (c + 3) * KCH);
            pwB = *(const float4*)(wg + (c + 3) * KCH);
        }
        mfma_chunk(Xs[1], Ws[1], wr, wc, ra, cb, ka, kb, acc0, acc1);
        if (c + 2 < NCH) {
            stage_store(Xs[0], Ws[0], sr, sc, pxA, pwA); // chunk c+2
            __syncthreads();
        }
    }

    double* pbase = part + (size_t)ks * N_TOK * NEXP;
#pragma unroll
    for (int rt = 0; rt < 2; ++rt) {
        const d4 accv = rt == 0 ? acc0 : acc1;
#pragma unroll
        for (int r = 0; r < 4; ++r) {
            const int p    = sf ? (q + 4 * r) : (4 * q + r);
            const int dtok = tr ? i16 : p;
            const int dex  = tr ? p : i16;
            const int tok  = tok0 + wr * 32 + rt * 16 + dtok;
            const int ex   = wc * 16 + dex;
            pbase[(size_t)tok * NEXP + ex] = accv[r];
        }
    }
}

// VALU fallback (R7 structure, proven math). Doubles as stats zeroer.
// Runs the full GEMM only if the MFMA layout is unresolved on this HW.
__global__ __launch_bounds__(512, 4) void gemm_valu_kernel(const float* __restrict__ X,
                                                           const float* __restrict__ W,
                                                           double* __restrict__ part,
                                                           float* __restrict__ stats) {
    if (blockIdx.x == 0 && threadIdx.x < 128)
        stats[threadIdx.x] = 0.f;                    // probsum + counts
    if (derive_flag() != 0) return;                  // MFMA path verified -> skip
    const int tt   = blockIdx.x >> 2;
    const int ks   = blockIdx.x & 3;
    const int tid  = threadIdx.x;
    const int lane = tid & 63;                       // expert
    const int wv   = tid >> 6;                       // 0..7
    const int tok0 = tt * 64;
    const int k0   = ks * KSEG;

    __shared__ double xs[64][18];
    __shared__ double wsh[16][66];

    double acc[8];
#pragma unroll
    for (int t = 0; t < 8; ++t) acc[t] = 0.0;

    const int sx_tok = tid >> 3;
    const int sx_k   = (tid & 7) * 2;
    const float* xg  = X + (size_t)(tok0 + sx_tok) * HDIM + k0 + sx_k;
    const int sw_k = tid >> 5;                       // 0..15
    const int sw_e = (tid & 31) * 2;                 // 0..62
    const float* wg0 = W + (size_t)sw_e * HDIM + k0 + sw_k;
    const float* wg1 = W + (size_t)(sw_e + 1) * HDIM + k0 + sw_k;

    float2 px = *(const float2*)xg;
    float  pa = *wg0, pb2 = *wg1;

    for (int c = 0; c < KSEG / 16; ++c) {
        __syncthreads();
        {
            double2 xv; xv.x = (double)px.x; xv.y = (double)px.y;
            *(double2*)&xs[sx_tok][sx_k] = xv;
            double2 wv2; wv2.x = (double)pa; wv2.y = (double)pb2;
            *(double2*)&wsh[sw_k][sw_e] = wv2;
        }
        __syncthreads();
        if (c + 1 < KSEG / 16) {
            px  = *(const float2*)(xg + (c + 1) * 16);
            pa  = wg0[(c + 1) * 16];
            pb2 = wg1[(c + 1) * 16];
        }
        double wr_[16];
#pragma unroll
        for (int j = 0; j < 16; ++j) wr_[j] = wsh[j][lane];
#pragma unroll
        for (int t = 0; t < 8; ++t) {
            const int trr = wv * 8 + t;
#pragma unroll
            for (int kp = 0; kp < 8; ++kp) {
                double2 xv = *(const double2*)&xs[trr][kp * 2];
                acc[t] = fma(xv.x, wr_[kp * 2],     acc[t]);
                acc[t] = fma(xv.y, wr_[kp * 2 + 1], acc[t]);
            }
        }
    }

    double* pb = part + ((size_t)ks * N_TOK + tok0 + wv * 8) * NEXP + lane;
#pragma unroll
    for (int t = 0; t < 8; ++t)
        pb[(size_t)t * NEXP] = acc[t];
}

// Top-k (R17-proven, ~15-18 us): 16 tok/block, 2-token-interleaved proven
// ladders (f32 score comparator, ties -> min idx), no fence/counter.
__global__ __launch_bounds__(256) void topk_kernel(const double* __restrict__ part,
                                                   float* __restrict__ outIdx,
                                                   float* __restrict__ outW,
                                                   float* __restrict__ stats) {
    __shared__ float sc_s[16][65];
    __shared__ float lds_counts[NEXP];
    __shared__ float psum_part[4][NEXP];
    const int tid  = threadIdx.x;
    const int lane = tid & 63;
    const int w    = tid >> 6;
    if (tid < NEXP) lds_counts[tid] = 0.f;

    const int t0 = blockIdx.x * 16;
#pragma unroll
    for (int p = 0; p < 4; ++p) {
        const int idx = p * 256 + tid;               // 0..1023
        const int t   = idx >> 6;
        const int e   = idx & 63;
        const double* pp = part + ((size_t)(t0 + t)) * NEXP + e;
        double l = (pp[0] + pp[(size_t)N_TOK * NEXP]) +
                   (pp[2 * (size_t)N_TOK * NEXP] + pp[3 * (size_t)N_TOK * NEXP]);
        sc_s[t][e] = (float)(1.0 / (1.0 + exp(-l)));
    }
    __syncthreads();

    float ps = 0.f;
#pragma unroll
    for (int i = 0; i < 4; i += 2) {                 // two tokens interleaved
        const int tA = w * 4 + i, tB = tA + 1;
        float sA = sc_s[tA][lane], sB = sc_s[tB][lane];

        float rsA = sA, rsB = sB;
#pragma unroll
        for (int off = 32; off; off >>= 1) {
            rsA += __shfl_xor(rsA, off);
            rsB += __shfl_xor(rsB, off);
        }
        ps += sA / (rsA + 1e-9f) + sB / (rsB + 1e-9f);

        float curA = sA, curB = sB;
        float denA = 0.f, denB = 0.f;
        int   wiA = 0, wiB = 0;
        float wvA = 0.f, wvB = 0.f;
#pragma unroll
        for (int k = 0; k < TOPK; ++k) {
            float mA = curA; int miA = lane;
            float mB = curB; int miB = lane;
#pragma unroll
            for (int off = 32; off; off >>= 1) {     // argmax, ties -> min idx
                float omA = __shfl_xor(mA, off);
                int   oiA = __shfl_xor(miA, off);
                float omB = __shfl_xor(mB, off);
                int   oiB = __shfl_xor(miB, off);
                if (omA > mA || (omA == mA && oiA < miA)) { mA = omA; miA = oiA; }
                if (omB > mB || (omB == mB && oiB < miB)) { mB = omB; miB = oiB; }
            }
            denA += mA; denB += mB;
            if (lane == k)   { wiA = miA; wvA = mA; wiB = miB; wvB = mB; }
            if (lane == miA) curA = -1e30f;
            if (lane == miB) curB = -1e30f;
        }
        if (lane < TOPK) {
            const int ta = t0 + tA, tb = t0 + tB;
            outIdx[(size_t)ta * TOPK + lane] = (float)wiA;
            outW  [(size_t)ta * TOPK + lane] = wvA / (denA + 1e-9f);
            outIdx[(size_t)tb * TOPK + lane] = (float)wiB;
            outW  [(size_t)tb * TOPK + lane] = wvB / (denB + 1e-9f);
            atomicAdd(&lds_counts[wiA], 1.f);
            atomicAdd(&lds_counts[wiB], 1.f);
        }
    }
    psum_part[w][lane] = ps;
    __syncthreads();
    if (tid < NEXP) {
        float tot = psum_part[0][tid] + psum_part[1][tid] +
                    psum_part[2][tid] + psum_part[3][tid];
        atomicAdd(&stats[tid], tot);                  // probsum
        atomicAdd(&stats[NEXP + tid], lds_counts[tid]); // counts
    }
}

// Separate aux kernel: dispatch boundary provides cross-XCD visibility of
// topk's device-scope atomics — no per-block fence (R15/R16 lesson).
__global__ void aux_kernel(const float* __restrict__ stats, float* __restrict__ out) {
    const int e = threadIdx.x;                        // 64 threads
    float prob = stats[e] / (float)N_TOK;
    float cnt  = stats[NEXP + e];
    float loadf = cnt / ((float)N_TOK * TOPK);
    float S = prob;
#pragma unroll
    for (int off = 32; off; off >>= 1) S += __shfl_xor(S, off);
    float pn = prob / (S + 1e-9f);
    float v  = loadf * pn;
#pragma unroll
    for (int off = 32; off; off >>= 1) v += __shfl_xor(v, off);
    if (e == 0) out[2 * N_TOK * TOPK] = 0.001f * v * (float)NEXP;
}

extern "C" void kernel_launch(void* const* d_in, const int* in_sizes, int n_in,
                              void* d_out, int out_size, void* d_ws, size_t ws_size,
                              hipStream_t stream) {
    (void)in_sizes; (void)n_in; (void)out_size; (void)ws_size;
    const float* X = (const float*)d_in[0];
    const float* W = (const float*)d_in[1];
    float* out = (float*)d_out;
    char*  ws  = (char*)d_ws;
    double* part  = (double*)(ws + PART_OFF);
    float*  stats = (float*)(ws + STATS_OFF);

    gemm_mfma_kernel<<<1024, 512, 0, stream>>>(X, W, part);
    gemm_valu_kernel<<<1024, 512, 0, stream>>>(X, W, part, stats);
    topk_kernel<<<1024, 256, 0, stream>>>(part, out, out + N_TOK * TOPK, stats);
    aux_kernel<<<1, 64, 0, stream>>>(stats, out);
}